// Round 1
// baseline (144.640 us; speedup 1.0000x reference)
//
#include <hip/hip_runtime.h>

#define B_   32
#define A_   3
#define H_   160
#define W_   160
#define HW_  (H_ * W_)      // 25600
#define NCLS 3
#define CH_  (A_ * 8)       // 24 channels

// ws layout (floats): [0]=conf_sq_sum  [1]=box_sum  [2]=cls_sum  [3]=conf_corr  [4]=valid_count
__global__ void zero_ws_kernel(float* ws) {
    if (threadIdx.x < 8) ws[threadIdx.x] = 0.0f;
}

__device__ __forceinline__ float sigmoidf_(float x) {
    return 1.0f / (1.0f + __expf(-x));
}

// Dense pass: sum of sigmoid(conf)^2 over all (b, a, h, w).
// Conf channel for anchor a is (a*8 + 4); each plane is HW_ contiguous floats.
// grid = (HW_/4/256, B_*A_), block = 256, each thread handles one float4.
__global__ void conf_kernel(const float* __restrict__ pred, float* __restrict__ ws) {
    int plane = blockIdx.y;               // 0..95
    int b = plane / A_;
    int a = plane - b * A_;
    const float4* src = (const float4*)(pred + (size_t)(b * CH_ + a * 8 + 4) * HW_);
    int i = blockIdx.x * blockDim.x + threadIdx.x;   // 0..6399
    float4 v = src[i];
    float s0 = sigmoidf_(v.x);
    float s1 = sigmoidf_(v.y);
    float s2 = sigmoidf_(v.z);
    float s3 = sigmoidf_(v.w);
    float sum = s0 * s0 + s1 * s1 + s2 * s2 + s3 * s3;

    // wave64 reduce
    #pragma unroll
    for (int off = 32; off > 0; off >>= 1)
        sum += __shfl_down(sum, off, 64);

    __shared__ float lds[4];
    int lane = threadIdx.x & 63;
    int wv   = threadIdx.x >> 6;
    if (lane == 0) lds[wv] = sum;
    __syncthreads();
    if (threadIdx.x == 0) {
        float t = lds[0] + lds[1] + lds[2] + lds[3];
        atomicAdd(ws + 0, t);
    }
}

// Sparse pass: one thread per target. Gathers 3 anchors x 7 channels.
__global__ void target_kernel(const float* __restrict__ pred,
                              const float* __restrict__ tgt,
                              float* __restrict__ ws, int N) {
    int i = blockIdx.x * blockDim.x + threadIdx.x;
    float box = 0.0f, cls = 0.0f, corr = 0.0f, cnt = 0.0f;
    if (i < N) {
        const float* t = tgt + (size_t)i * 6;
        int   b  = (int)t[0];
        int   c  = (int)t[1];
        float tx = t[2], ty = t[3], tw = t[4], th = t[5];
        int gx = (int)(tx * W_);
        int gy = (int)(ty * H_);
        bool valid = (gx < W_) && (gy < H_);
        // mode='drop' bounds check on the scatter indices
        if (valid && (unsigned)b < (unsigned)B_ &&
            (unsigned)gy < (unsigned)H_ && (unsigned)gx < (unsigned)W_) {
            cnt = 1.0f;
            int ci = (c >= 0 && c < NCLS) ? c : NCLS;   // NCLS => dropped => all-zero one-hot
            size_t cell = (size_t)gy * W_ + gx;
            #pragma unroll
            for (int a = 0; a < A_; ++a) {
                const float* p = pred + (size_t)(b * CH_ + a * 8) * HW_ + cell;
                float sx = sigmoidf_(p[0 * HW_]);
                float sy = sigmoidf_(p[1 * HW_]);
                float ew = __expf(p[2 * HW_]);
                float eh = __expf(p[3 * HW_]);
                box += (sx - tx) * (sx - tx) + (sy - ty) * (sy - ty)
                     + (ew - tw) * (ew - tw) + (eh - th) * (eh - th);
                corr += 1.0f - 2.0f * sigmoidf_(p[4 * HW_]);
                #pragma unroll
                for (int k = 0; k < NCLS; ++k) {
                    float s  = sigmoidf_(p[(5 + k) * HW_]);
                    float tv = (k == ci) ? 1.0f : 0.0f;
                    cls += (s - tv) * (s - tv);
                }
            }
        }
    }
    // wave64 reduce all four accumulators, one atomicAdd set per wave
    #pragma unroll
    for (int off = 32; off > 0; off >>= 1) {
        box  += __shfl_down(box,  off, 64);
        cls  += __shfl_down(cls,  off, 64);
        corr += __shfl_down(corr, off, 64);
        cnt  += __shfl_down(cnt,  off, 64);
    }
    if ((threadIdx.x & 63) == 0) {
        atomicAdd(ws + 1, box);
        atomicAdd(ws + 2, cls);
        atomicAdd(ws + 3, corr);
        atomicAdd(ws + 4, cnt);
    }
}

__global__ void finalize_kernel(const float* __restrict__ ws, float* __restrict__ out) {
    float n = ws[4] * (float)A_;                       // mask entries = A per valid cell
    float loss_box  = ws[1] / (n * 4.0f);
    float loss_conf = (ws[0] + ws[3]) / (float)(B_ * A_ * HW_);
    float loss_cls  = ws[2] / (n * (float)NCLS);
    out[0] = 5.0f * loss_box + loss_conf + loss_cls;
}

extern "C" void kernel_launch(void* const* d_in, const int* in_sizes, int n_in,
                              void* d_out, int out_size, void* d_ws, size_t ws_size,
                              hipStream_t stream) {
    const float* pred = (const float*)d_in[0];
    const float* tgt  = (const float*)d_in[1];
    float* ws  = (float*)d_ws;
    float* out = (float*)d_out;
    int N = in_sizes[1] / 6;   // 512

    zero_ws_kernel<<<1, 64, 0, stream>>>(ws);
    conf_kernel<<<dim3(HW_ / 4 / 256, B_ * A_), 256, 0, stream>>>(pred, ws);
    target_kernel<<<(N + 255) / 256, 256, 0, stream>>>(pred, tgt, ws, N);
    finalize_kernel<<<1, 1, 0, stream>>>(ws, out);
}

// Round 2
// 113.458 us; speedup vs baseline: 1.2748x; 1.2748x over previous
//
#include <hip/hip_runtime.h>

#define B_   32
#define A_   3
#define H_   160
#define W_   160
#define HW_  (H_ * W_)      // 25600
#define NCLS 3
#define CH_  (A_ * 8)       // 24 channels

#define DENSE_BLOCKS_PER_PLANE 5
#define NPLANES (B_ * A_)                              // 96
#define NDENSE  (DENSE_BLOCKS_PER_PLANE * NPLANES)     // 480
// ws layout (floats):
//  [0 .. 479]           dense conf sigma^2 partials, one per dense block
//  [480 + tb*4 + 0..3]  target-block partials: box, cls, corr, cnt

__device__ __forceinline__ float sigmoidf_(float x) {
    return 1.0f / (1.0f + __expf(-x));
}

// returns full-block sum, valid on threadIdx.x == 0 only. block = 256 (4 waves)
__device__ __forceinline__ float block_reduce256(float v, float* lds4) {
    #pragma unroll
    for (int off = 32; off > 0; off >>= 1)
        v += __shfl_down(v, off, 64);
    int lane = threadIdx.x & 63, wv = threadIdx.x >> 6;
    if (lane == 0) lds4[wv] = v;
    __syncthreads();
    return lds4[0] + lds4[1] + lds4[2] + lds4[3];
}

__global__ void fused_kernel(const float* __restrict__ pred,
                             const float* __restrict__ tgt,
                             float* __restrict__ ws, int N) {
    __shared__ float lds[4 * 4];
    int blk = blockIdx.x;

    if (blk < NDENSE) {
        // ---- dense pass: sum sigmoid(conf)^2 over one slice of one plane ----
        int plane = blk / DENSE_BLOCKS_PER_PLANE;       // 0..95
        int bx    = blk - plane * DENSE_BLOCKS_PER_PLANE;
        int b = plane / A_;
        int a = plane - b * A_;
        const float4* src = (const float4*)(pred + (size_t)(b * CH_ + a * 8 + 4) * HW_);
        float sum = 0.0f;
        int i = bx * 256 + threadIdx.x;                 // 0..1279
        #pragma unroll
        for (int k = 0; k < DENSE_BLOCKS_PER_PLANE; ++k) {
            float4 v = src[i + k * (DENSE_BLOCKS_PER_PLANE * 256)];
            float s0 = sigmoidf_(v.x), s1 = sigmoidf_(v.y);
            float s2 = sigmoidf_(v.z), s3 = sigmoidf_(v.w);
            sum += s0 * s0 + s1 * s1 + s2 * s2 + s3 * s3;
        }
        float t = block_reduce256(sum, lds);
        if (threadIdx.x == 0) ws[blk] = t;
    } else {
        // ---- sparse pass: one thread per target ----
        int tb = blk - NDENSE;
        int i  = tb * 256 + threadIdx.x;
        float box = 0.0f, cls = 0.0f, corr = 0.0f, cnt = 0.0f;
        if (i < N) {
            const float* t = tgt + (size_t)i * 6;
            int   b  = (int)t[0];
            int   c  = (int)t[1];
            float tx = t[2], ty = t[3], tw = t[4], th = t[5];
            int gx = (int)(tx * W_);
            int gy = (int)(ty * H_);
            bool valid = (gx < W_) && (gy < H_);
            if (valid && (unsigned)b < (unsigned)B_ &&
                (unsigned)gy < (unsigned)H_ && (unsigned)gx < (unsigned)W_) {
                cnt = 1.0f;
                int ci = (c >= 0 && c < NCLS) ? c : NCLS;
                size_t cell = (size_t)gy * W_ + gx;
                #pragma unroll
                for (int a = 0; a < A_; ++a) {
                    const float* p = pred + (size_t)(b * CH_ + a * 8) * HW_ + cell;
                    float sx = sigmoidf_(p[0 * HW_]);
                    float sy = sigmoidf_(p[1 * HW_]);
                    float ew = __expf(p[2 * HW_]);
                    float eh = __expf(p[3 * HW_]);
                    box += (sx - tx) * (sx - tx) + (sy - ty) * (sy - ty)
                         + (ew - tw) * (ew - tw) + (eh - th) * (eh - th);
                    corr += 1.0f - 2.0f * sigmoidf_(p[4 * HW_]);
                    #pragma unroll
                    for (int k = 0; k < NCLS; ++k) {
                        float s  = sigmoidf_(p[(5 + k) * HW_]);
                        float tv = (k == ci) ? 1.0f : 0.0f;
                        cls += (s - tv) * (s - tv);
                    }
                }
            }
        }
        // wave-reduce each accumulator, then combine 4 waves via LDS
        #pragma unroll
        for (int off = 32; off > 0; off >>= 1) {
            box  += __shfl_down(box,  off, 64);
            cls  += __shfl_down(cls,  off, 64);
            corr += __shfl_down(corr, off, 64);
            cnt  += __shfl_down(cnt,  off, 64);
        }
        int lane = threadIdx.x & 63, wv = threadIdx.x >> 6;
        if (lane == 0) {
            lds[wv * 4 + 0] = box;  lds[wv * 4 + 1] = cls;
            lds[wv * 4 + 2] = corr; lds[wv * 4 + 3] = cnt;
        }
        __syncthreads();
        if (threadIdx.x == 0) {
            float* o = ws + NDENSE + tb * 4;
            #pragma unroll
            for (int j = 0; j < 4; ++j)
                o[j] = lds[0 * 4 + j] + lds[1 * 4 + j] + lds[2 * 4 + j] + lds[3 * 4 + j];
        }
    }
}

__global__ void reduce_kernel(const float* __restrict__ ws,
                              float* __restrict__ out, int nTargetBlocks) {
    __shared__ float lds[4];
    float s = 0.0f;
    for (int j = threadIdx.x; j < NDENSE; j += 256) s += ws[j];
    float conf_sq = block_reduce256(s, lds);
    if (threadIdx.x == 0) {
        float box = 0.0f, cls = 0.0f, corr = 0.0f, cnt = 0.0f;
        for (int tb = 0; tb < nTargetBlocks; ++tb) {
            const float* o = ws + NDENSE + tb * 4;
            box += o[0]; cls += o[1]; corr += o[2]; cnt += o[3];
        }
        float n = cnt * (float)A_;   // mask entries = A anchors per valid cell
        float loss_box  = box / (n * 4.0f);
        float loss_conf = (conf_sq + corr) / (float)(B_ * A_ * HW_);
        float loss_cls  = cls / (n * (float)NCLS);
        out[0] = 5.0f * loss_box + loss_conf + loss_cls;
    }
}

extern "C" void kernel_launch(void* const* d_in, const int* in_sizes, int n_in,
                              void* d_out, int out_size, void* d_ws, size_t ws_size,
                              hipStream_t stream) {
    const float* pred = (const float*)d_in[0];
    const float* tgt  = (const float*)d_in[1];
    float* ws  = (float*)d_ws;
    float* out = (float*)d_out;
    int N = in_sizes[1] / 6;                   // 512
    int nTargetBlocks = (N + 255) / 256;       // 2

    fused_kernel<<<NDENSE + nTargetBlocks, 256, 0, stream>>>(pred, tgt, ws, N);
    reduce_kernel<<<1, 256, 0, stream>>>(ws, out, nTargetBlocks);
}